// Round 1
// baseline (31674.667 us; speedup 1.0000x reference)
//
#include <hip/hip_runtime.h>
#include <math.h>

#define B 64
#define L 128
#define N_ 512
#define E_ 512
#define H_ 512
#define NEG -1e9f

// ---------------- precompute kernels ----------------

__global__ __launch_bounds__(512) void k_transpose(const float* __restrict__ Wq,
                                                   float* __restrict__ WqT) {
  int j = blockIdx.x, hp = threadIdx.x;
  WqT[hp * H_ + j] = Wq[j * H_ + hp];
}

__global__ __launch_bounds__(256) void k_init(const float* __restrict__ state,
                                              float* __restrict__ hb,
                                              float* __restrict__ cov) {
  int i = blockIdx.x * 256 + threadIdx.x;
  if (i < B * H_) hb[i] = state[i];
  if (i < B * N_) cov[i] = 0.f;
}

// vk[b,n,k] = sum_h value[b,n,h] * Wk[k,h]
__global__ __launch_bounds__(256) void k_vk(const float* __restrict__ value,
                                            const float* __restrict__ Wk,
                                            float* __restrict__ vk) {
  int k0 = blockIdx.x * 64, n0 = blockIdx.y * 64, b = blockIdx.z;
  int tid = threadIdx.x;
  int tn = tid >> 4, tk = tid & 15;
  __shared__ float Vs[64][33];
  __shared__ float Ws[64][33];
  const float* vb = value + (size_t)b * N_ * H_;
  float acc[4][4] = {};
  for (int h0 = 0; h0 < H_; h0 += 32) {
#pragma unroll
    for (int e = 0; e < 8; ++e) {
      int idx = tid + e * 256;
      int r = idx >> 5, c = idx & 31;
      Vs[r][c] = vb[(size_t)(n0 + r) * H_ + h0 + c];
      Ws[r][c] = Wk[(size_t)(k0 + r) * H_ + h0 + c];
    }
    __syncthreads();
#pragma unroll
    for (int c = 0; c < 32; ++c) {
      float av[4], wv[4];
#pragma unroll
      for (int i = 0; i < 4; ++i) av[i] = Vs[tn * 4 + i][c];
#pragma unroll
      for (int jq = 0; jq < 4; ++jq) wv[jq] = Ws[tk * 4 + jq][c];
#pragma unroll
      for (int i = 0; i < 4; ++i)
#pragma unroll
        for (int jq = 0; jq < 4; ++jq) acc[i][jq] += av[i] * wv[jq];
    }
    __syncthreads();
  }
  float* vkb = vk + (size_t)b * N_ * H_;
#pragma unroll
  for (int i = 0; i < 4; ++i) {
    float4 v4 = make_float4(acc[i][0], acc[i][1], acc[i][2], acc[i][3]);
    *(float4*)&vkb[(size_t)(n0 + tn * 4 + i) * H_ + k0 + tk * 4] = v4;
  }
}

// ---------------- per-step: attention ----------------
// one workgroup per batch; q matvec, scores+softmax+context in one kernel.
__global__ __launch_bounds__(512) void k_attn(
    const float* __restrict__ vk, const float* __restrict__ WqT,
    const float* __restrict__ value, const float* __restrict__ vmask,
    const float* __restrict__ b_attn, const float* __restrict__ w_cov,
    const float* __restrict__ v_attn, const float* __restrict__ h_in,
    float* __restrict__ cov, float* __restrict__ ctx,
    float* __restrict__ attn_out, int t) {
  int b = blockIdx.x;
  int tid = threadIdx.x;
  __shared__ float hs[H_], qs[H_], wc[H_], va[H_], ba[H_];
  __shared__ float sc[N_], red[512], covs[N_];

  hs[tid] = h_in[b * H_ + tid];
  wc[tid] = w_cov[tid];
  va[tid] = v_attn[tid];
  ba[tid] = b_attn[tid];
  covs[tid] = cov[b * N_ + tid];
  __syncthreads();

  // q[j] = sum_h' h[h'] * Wq[j,h']  (WqT[h',j] coalesced over j)
  {
    float acc = 0.f;
#pragma unroll 8
    for (int hp = 0; hp < H_; ++hp) acc += WqT[hp * H_ + tid] * hs[hp];
    qs[tid] = acc;
  }
  __syncthreads();

  // scores: 8 waves, each 64 rows; lanes over h with shuffle reduce
  int w = tid >> 6, l = tid & 63;
  const float* vkb = vk + (size_t)b * N_ * H_;
  for (int n = w * 64; n < w * 64 + 64; ++n) {
    float p = 0.f;
    const float* row = vkb + (size_t)n * H_;
    float cv = covs[n];
#pragma unroll
    for (int i = 0; i < 8; ++i) {
      int h = i * 64 + l;
      float e = qs[h] + row[h] + cv * wc[h] + ba[h];
      p += fmaxf(e, 0.f) * va[h];
    }
#pragma unroll
    for (int off = 32; off; off >>= 1) p += __shfl_xor(p, off);
    if (l == 0) sc[n] = p;
  }
  __syncthreads();

  // mask + softmax over n (blockDim == N_)
  float s_val = (vmask[b * N_ + tid] > 0.f) ? sc[tid] : NEG;
  red[tid] = s_val;
  __syncthreads();
#pragma unroll
  for (int s = 256; s > 0; s >>= 1) {
    if (tid < s) red[tid] = fmaxf(red[tid], red[tid + s]);
    __syncthreads();
  }
  float m = red[0];
  __syncthreads();
  float p = expf(s_val - m);
  red[tid] = p;
  __syncthreads();
#pragma unroll
  for (int s = 256; s > 0; s >>= 1) {
    if (tid < s) red[tid] += red[tid + s];
    __syncthreads();
  }
  float at = p * (1.f / red[0]);
  cov[b * N_ + tid] = covs[tid] + at;
  attn_out[((size_t)b * L + t) * N_ + tid] = at;
  sc[tid] = at;
  __syncthreads();

  // context[h] = sum_n attn[n] * value[b,n,h] (coalesced over h)
  {
    float acc = 0.f;
    const float* vb = value + (size_t)b * N_ * H_ + tid;
#pragma unroll 4
    for (int n = 0; n < N_; ++n) acc += sc[n] * vb[(size_t)n * H_];
    ctx[b * H_ + tid] = acc;
  }
}

// ---------------- per-step: GRU ----------------
// 128 WGs, each owns 4 output rows j (x3 gates) for all 64 batches:
// weights are read exactly once per step across the grid, wave-uniform rows.
__global__ __launch_bounds__(256) void k_gru(
    const float* __restrict__ emb, const float* __restrict__ ctx,
    const float* __restrict__ W_ih, const float* __restrict__ W_hh,
    const float* __restrict__ b_ih, const float* __restrict__ b_hh,
    const float* __restrict__ h_in, float* __restrict__ h_out,
    float* __restrict__ out_h, int t) {
  int tid = threadIdx.x;
  int b = tid & 63;
  int jj = tid >> 6;  // == wave id, uniform per wave
  int j = __builtin_amdgcn_readfirstlane(blockIdx.x * 4 + jj);
  __shared__ float xt[64][65];

  float ar = b_ih[j], az = b_ih[j + H_], an = b_ih[j + 2 * H_];
  const float* wr = W_ih + (size_t)j * (E_ + H_);
  const float* wz = W_ih + (size_t)(j + H_) * (E_ + H_);
  const float* wn = W_ih + (size_t)(j + 2 * H_) * (E_ + H_);
  for (int i0 = 0; i0 < E_ + H_; i0 += 64) {
    __syncthreads();
#pragma unroll
    for (int e = 0; e < 16; ++e) {
      int idx = tid + e * 256;
      int r = idx >> 6, c = idx & 63;
      int i = i0 + c;
      xt[r][c] = (i < E_) ? emb[((size_t)r * L + t) * E_ + i]
                          : ctx[r * H_ + (i - E_)];
    }
    __syncthreads();
#pragma unroll
    for (int c = 0; c < 64; ++c) {
      float x = xt[b][c];
      ar += x * wr[i0 + c];
      az += x * wz[i0 + c];
      an += x * wn[i0 + c];
    }
  }

  float gr = b_hh[j], gz = b_hh[j + H_], gn = b_hh[j + 2 * H_];
  const float* ur = W_hh + (size_t)j * H_;
  const float* uz = W_hh + (size_t)(j + H_) * H_;
  const float* un = W_hh + (size_t)(j + 2 * H_) * H_;
  for (int i0 = 0; i0 < H_; i0 += 64) {
    __syncthreads();
#pragma unroll
    for (int e = 0; e < 16; ++e) {
      int idx = tid + e * 256;
      int r = idx >> 6, c = idx & 63;
      xt[r][c] = h_in[r * H_ + i0 + c];
    }
    __syncthreads();
#pragma unroll
    for (int c = 0; c < 64; ++c) {
      float x = xt[b][c];
      gr += x * ur[i0 + c];
      gz += x * uz[i0 + c];
      gn += x * un[i0 + c];
    }
  }

  float r = 1.f / (1.f + expf(-(ar + gr)));
  float z = 1.f / (1.f + expf(-(az + gz)));
  float nn = tanhf(an + r * gn);
  float hp = h_in[b * H_ + j];
  float hv = (1.f - z) * nn + z * hp;
  h_out[b * H_ + j] = hv;
  out_h[((size_t)b * L + t) * H_ + j] = hv;
}

// ---------------- launch ----------------

extern "C" void kernel_launch(void* const* d_in, const int* in_sizes, int n_in,
                              void* d_out, int out_size, void* d_ws, size_t ws_size,
                              hipStream_t stream) {
  const float* emb    = (const float*)d_in[0];
  const float* value  = (const float*)d_in[1];
  const float* vmask  = (const float*)d_in[2];
  const float* state  = (const float*)d_in[3];
  const float* Wq     = (const float*)d_in[4];
  const float* Wk     = (const float*)d_in[5];
  const float* b_attn = (const float*)d_in[6];
  const float* w_cov  = (const float*)d_in[7];
  const float* v_attn = (const float*)d_in[8];
  const float* W_ih   = (const float*)d_in[9];
  const float* W_hh   = (const float*)d_in[10];
  const float* b_ih   = (const float*)d_in[11];
  const float* b_hh   = (const float*)d_in[12];

  float* out = (float*)d_out;
  float* attn_out = out + (size_t)B * L * H_;

  float* ws  = (float*)d_ws;
  float* vk  = ws;                          // B*N*H          (16.78M f)
  float* WqT = vk + (size_t)B * N_ * H_;    // H*H            (0.26M f)
  float* hb  = WqT + (size_t)H_ * H_;       // 2*B*H          (65.5K f)
  float* cov = hb + (size_t)2 * B * H_;     // B*N            (32.8K f)
  float* ctx = cov + (size_t)B * N_;        // B*H            (32.8K f)

  k_transpose<<<H_, 512, 0, stream>>>(Wq, WqT);
  k_init<<<128, 256, 0, stream>>>(state, hb, cov);
  k_vk<<<dim3(8, 8, B), 256, 0, stream>>>(value, Wk, vk);

  for (int t = 0; t < L; ++t) {
    const float* hin = hb + (size_t)(t & 1) * B * H_;
    float* hout = hb + (size_t)((t + 1) & 1) * B * H_;
    k_attn<<<B, 512, 0, stream>>>(vk, WqT, value, vmask, b_attn, w_cov, v_attn,
                                  hin, cov, ctx, attn_out, t);
    k_gru<<<128, 256, 0, stream>>>(emb, ctx, W_ih, W_hh, b_ih, b_hh,
                                   hin, hout, out, t);
  }
}